// Round 5
// baseline (11.928 us; speedup 1.0000x reference)
//
#include <hip/hip_runtime.h>

#define B_    8
#define N_    128
#define NB_   32
#define NORB_ 128
#define RPB   32     // rows per block
#define OPB   16     // orbitals per block
#define NQ    32     // K-chunks of 32 kl
#define THREADS 1024
#define RPAD  20     // red row stride (16 used + 4 pad)

__global__ __launch_bounds__(THREADS, 4) void bobf_kernel(
    const float* __restrict__ chi,
    const float* __restrict__ W,
    float* __restrict__ out)
{
    __shared__ float Sp[32][NB_];                        // 4 KB
    __shared__ float S[NB_];
    __shared__ __align__(16) float xT[NB_][RPB];         // xT[l][r], 4 KB
    __shared__ __align__(16) float red[NQ][RPB][RPAD];   // 80 KB

    const int t   = threadIdx.x;
    const int blk = blockIdx.x;
    const int b    = blk >> 5;           // 0..7
    const int rowg = (blk >> 3) & 3;     // 0..3
    const int og   = blk & 7;            // 0..7
    const int i0   = rowg * RPB;
    const int o0   = og * OPB;

    // ---- Stage 1: S[k] partials (coalesced full-chi[b] read) + xT build ----
    {
        const int k = t & 31;
        const int g = t >> 5;                            // 0..31, 4 rows each
        const float* base = chi + (b * N_) * NB_ + k;
        float s = 0.f;
        #pragma unroll
        for (int jj = 0; jj < 4; ++jj) s += base[(g * 4 + jj) * NB_];
        Sp[g][k] = s;
    }
    {
        const int l = t >> 5, r = t & 31;                // LDS-write friendly (bank = r)
        xT[l][r] = chi[(b * N_ + i0 + r) * NB_ + l];
    }
    __syncthreads();
    if (t < NB_) {
        float s = 0.f;
        #pragma unroll
        for (int g = 0; g < 32; ++g) s += Sp[g][t];
        S[t] = s;
    }
    __syncthreads();

    // ---- Main: thread = (q, rg, oq); k == q is constant within a chunk ----
    const int q  = t >> 5;               // K-chunk: kl in [q*32, q*32+32)
    const int w_ = t & 31;
    const int rg = w_ >> 2;              // 0..7
    const int oq = w_ & 3;               // 0..3
    const int r0 = rg * 4;

    const float inv = 1.0f / (float)(N_ - 1);
    float4 yv;
    {
        const float4 xq = *(const float4*)&xT[q][r0];    // x[r0..r0+3][q]
        const float Sq = S[q];
        yv.x = (Sq - xq.x) * inv;
        yv.y = (Sq - xq.y) * inv;
        yv.z = (Sq - xq.z) * inv;
        yv.w = (Sq - xq.w) * inv;
    }

    const float4* Wf = (const float4*)(W + (q * 32) * NORB_ + o0 + oq * 4);
    const float*  xjp = &xT[0][r0];

    float4 a0 = {0,0,0,0}, a1 = {0,0,0,0}, a2 = {0,0,0,0}, a3 = {0,0,0,0};
    #pragma unroll 8
    for (int j = 0; j < 32; ++j) {
        const float4 xv = *(const float4*)(xjp + j * RPB);   // xT[j][r0..r0+3], broadcast
        const float4 wv = Wf[j * (NORB_ / 4)];               // W[q*32+j][o..o+3]
        const float p0 = yv.x * xv.x;                        // p[kl][r0+..] rebuilt in-reg
        const float p1 = yv.y * xv.y;
        const float p2 = yv.z * xv.z;
        const float p3 = yv.w * xv.w;
        a0.x += p0 * wv.x; a0.y += p0 * wv.y; a0.z += p0 * wv.z; a0.w += p0 * wv.w;
        a1.x += p1 * wv.x; a1.y += p1 * wv.y; a1.z += p1 * wv.z; a1.w += p1 * wv.w;
        a2.x += p2 * wv.x; a2.y += p2 * wv.y; a2.z += p2 * wv.z; a2.w += p2 * wv.w;
        a3.x += p3 * wv.x; a3.y += p3 * wv.y; a3.z += p3 * wv.z; a3.w += p3 * wv.w;
    }

    // ---- Epilogue: per-chunk partials -> LDS, then 32-way reduce ----
    {
        float* rq = &red[q][0][0] + oq * 4;
        *(float4*)&rq[(r0 + 0) * RPAD] = a0;
        *(float4*)&rq[(r0 + 1) * RPAD] = a1;
        *(float4*)&rq[(r0 + 2) * RPAD] = a2;
        *(float4*)&rq[(r0 + 3) * RPAD] = a3;
    }
    __syncthreads();
    if (t < RPB * OPB) {                 // 512 outputs
        const int r = t >> 4, o = t & 15;
        float v = 0.f;
        #pragma unroll
        for (int qq = 0; qq < NQ; ++qq) v += red[qq][r][o];
        out[(b * N_ + i0 + r) * NORB_ + o0 + o] = v;
    }
}

extern "C" void kernel_launch(void* const* d_in, const int* in_sizes, int n_in,
                              void* d_out, int out_size, void* d_ws, size_t ws_size,
                              hipStream_t stream) {
    const float* chi = (const float*)d_in[0];
    const float* W   = (const float*)d_in[1];
    float* out = (float*)d_out;
    dim3 grid(256);                      // 8 b x 4 rowg x 8 og
    dim3 block(THREADS);
    hipLaunchKernelGGL(bobf_kernel, grid, block, 0, stream, chi, W, out);
}